// Round 15
// baseline (295.662 us; speedup 1.0000x reference)
//
#include <hip/hip_runtime.h>

#define NDIM 1024
#define CH 16
#define ROW_F4 4096   // float4 per W row (1024*16/4)

typedef float fvec4 __attribute__((ext_vector_type(4)));

#define FUSED_NB  4096
#define REDUCE_NB 163
#define SMALLS_NB 64

__device__ inline float4 f4add(float4 a, float4 b) {
    return make_float4(a.x + b.x, a.y + b.y, a.z + b.z, a.w + b.w);
}
__device__ inline float4 f4zero() { return make_float4(0.f, 0.f, 0.f, 0.f); }

__device__ inline void spin_acquire(unsigned* ctr, unsigned target) {
    if (threadIdx.x == 0) {
        while (__hip_atomic_load(ctr, __ATOMIC_ACQUIRE, __HIP_MEMORY_SCOPE_AGENT)
               != target)
            __builtin_amdgcn_s_sleep(8);
        __threadfence();   // agent acquire: buffer_inv (L1+L2) for the whole CU/XCD
    }
    __syncthreads();
}
__device__ inline void signal_release(unsigned* ctr) {
    __syncthreads();       // all threads' stores issued
    if (threadIdx.x == 0) {
        __threadfence();   // agent release: wbL2 -> visible cross-XCD
        __hip_atomic_fetch_add(ctr, 1u, __ATOMIC_RELEASE, __HIP_MEMORY_SCOPE_AGENT);
    }
}

// ---------------------------------------------------------------------------
// k_phase1: fused(4096 blocks) + reduce(163) + smalls(64) in ONE dispatch,
// ordered by device-scope counters. Bodies are verbatim r8-proven kernels.
// LDS: 33 KB union -> 4 blocks/CU -> 1024 co-resident; spinners (227) < 1024
// so the fused phase can always progress: no deadlock for any dispatch order.
// ---------------------------------------------------------------------------
__global__ __launch_bounds__(256) void k_phase1(const float* __restrict__ W1,
                                                const float* __restrict__ W2,
                                                const float* __restrict__ b1,
                                                const float* __restrict__ b2,
                                                const float* __restrict__ th0,
                                                const float* __restrict__ th1,
                                                const float* __restrict__ th2,
                                                const float* __restrict__ th3,
                                                const float* __restrict__ bias0,
                                                const float* __restrict__ bias1,
                                                const float* __restrict__ bias2,
                                                const float* __restrict__ bias3,
                                                float* __restrict__ rowpart,
                                                float* __restrict__ colpart,
                                                float* __restrict__ tiletot,
                                                float* __restrict__ rowsumF,
                                                float* __restrict__ colsumF,
                                                float* __restrict__ sums,
                                                float* __restrict__ R0, float* __restrict__ C0,
                                                float* __restrict__ R1, float* __restrict__ C1,
                                                float* __restrict__ out2, float* __restrict__ out3,
                                                unsigned* __restrict__ ctr) {
    __shared__ float4 smem[8 * 258 + 32];      // 33,280 B, shared by all phases
    int t   = threadIdx.x;
    int bid = blockIdx.x;

    if (bid < FUSED_NB) {
        // ----- fused: row/col partials + tile totals (r8 verbatim) -----
        int jt = bid & 15, it = (bid >> 4) & 127, z = bid >> 11;
        const float4* base = (const float4*)(z ? W2 : W1)
                           + (size_t)it * 8 * ROW_F4 + jt * 256 + t;
        float4 (*tile)[258] = (float4(*)[258])smem;
        float4* rtot = smem + 8 * 258;
        float4 colacc = f4zero();
#pragma unroll
        for (int r = 0; r < 8; ++r) {
            float4 v = base[(size_t)r * ROW_F4];
            colacc = f4add(colacc, v);
            tile[r][t] = v;
        }
        ((float4*)colpart)[(size_t)(z * 128 + it) * 4096 + jt * 256 + t] = colacc;
        __syncthreads();
        if (t < 32) {
            int r = t >> 2, cq = t & 3;
            float4 s = f4zero();
#pragma unroll
            for (int jl = 0; jl < 64; ++jl) s = f4add(s, tile[r][jl * 4 + cq]);
            ((float4*)rowpart)[(size_t)(z * 16 + jt) * 4096 + (it * 8 + r) * 4 + cq] = s;
            rtot[t] = s;
        }
        __syncthreads();
        if (t < 4) {
            float4 s = f4zero();
#pragma unroll
            for (int r = 0; r < 8; ++r) s = f4add(s, rtot[r * 4 + t]);
            ((float4*)tiletot)[(size_t)(z * 2048 + it * 16 + jt) * 4 + t] = s;
        }
        signal_release(&ctr[0]);
        return;
    }

    if (bid < FUSED_NB + REDUCE_NB) {
        // ----- reduce (r8 k_reduce verbatim, behind spin) -----
        int b = bid - FUSED_NB;
        if (b < 161) spin_acquire(&ctr[0], FUSED_NB);   // b1/b2 blocks skip
        if (b < 128) {
            const float4* cp = (const float4*)colpart;
            int o = b * 64 + (t & 63);
            int p = t >> 6;
            int z = o >> 12, rem = o & 4095;
            float4 s = f4zero();
#pragma unroll 8
            for (int k = 0; k < 32; ++k)
                s = f4add(s, cp[(size_t)(z * 128 + p * 32 + k) * 4096 + rem]);
            float4* lds = smem;
            lds[t] = s;
            __syncthreads();
            if (t < 64) {
                float4 r = f4add(f4add(lds[t], lds[t + 64]),
                                 f4add(lds[t + 128], lds[t + 192]));
                ((float4*)colsumF)[o] = r;
            }
        } else if (b < 160) {
            const float4* rp = (const float4*)rowpart;
            int o = (b - 128) * 256 + t;
            int z = o >> 12, rem = o & 4095;
            float4 s = f4zero();
#pragma unroll
            for (int k = 0; k < 16; ++k)
                s = f4add(s, rp[(size_t)(z * 16 + k) * 4096 + rem]);
            ((float4*)rowsumF)[o] = s;
        } else if (b == 160) {
            int c = t & 15, p = (t >> 4) & 7, z = t >> 7;
            float s = 0.f;
#pragma unroll 8
            for (int m = 0; m < 256; ++m)
                s += tiletot[(size_t)(z * 2048 + p * 256 + m) * 16 + c];
            float* ldsA = (float*)smem;                 // [2][8][16]
            ldsA[(z * 8 + p) * 16 + c] = s;
            __syncthreads();
            if (t < 32) {
                int zz = t >> 4, cc = t & 15;
                float r = 0.f;
#pragma unroll
                for (int q = 0; q < 8; ++q) r += ldsA[(zz * 8 + q) * 16 + cc];
                sums[zz * 16 + cc] = r;
            }
        } else {
            int w = b - 161;
            const float* src = w ? b2 : b1;
            int c = t & 15, p = t >> 4;
            float s = 0.f;
#pragma unroll 8
            for (int m = 0; m < 64; ++m)
                s += src[(size_t)(p * 64 + m) * 16 + c];
            float* ldsB = (float*)smem;                 // [16][16]
            ldsB[p * 16 + c] = s;
            __syncthreads();
            if (t < 16) {
                float r = 0.f;
#pragma unroll
                for (int q = 0; q < 16; ++q) r += ldsB[q * 16 + t];
                sums[32 + w * 16 + t] = r;
            }
        }
        signal_release(&ctr[1]);
        return;
    }

    // ----- smalls (r8 k_smalls verbatim, behind spin) -----
    spin_acquire(&ctr[1], REDUCE_NB);
    int sblk = bid - FUSED_NB - REDUCE_NB;
    int gt = sblk * 256 + t;
    int i = gt >> 4, o = gt & 15;
    const float* rs1 = rowsumF + i * 16;
    const float* rs2 = rowsumF + 16384 + i * 16;
    const float* cs1 = colsumF + i * 16;
    const float* cs2 = colsumF + 16384 + i * 16;
    const float* b1i = b1 + i * 16;
    const float* b2i = b2 + i * 16;
    float r0 = 0.f, c0a = 0.f, r1 = 0.f, c1a = 0.f, o2 = 0.f, o3 = 0.f;
    float k0 = 0.f, k1 = 0.f, k2 = 0.f, k3 = 0.f;
#pragma unroll
    for (int c = 0; c < 16; ++c) {
        float sW1 = sums[c], sW2 = sums[16 + c], sb1 = sums[32 + c], sb2 = sums[48 + c];
        r0  += rs1[c] * th0[(1 * 16 + c) * 16 + o];
        c0a += cs1[c] * th0[(2 * 16 + c) * 16 + o]
             + rs2[c] * th0[(4 * 16 + c) * 16 + o]
             + b1i[c] * th0[(6 * 16 + c) * 16 + o];
        k0  += sW1 * th0[(3 * 16 + c) * 16 + o] + sW2 * th0[(5 * 16 + c) * 16 + o]
             + sb1 * th0[(7 * 16 + c) * 16 + o] + sb2 * th0[(8 * 16 + c) * 16 + o];
        r1  += cs1[c] * th1[(0 * 16 + c) * 16 + o]
             + rs2[c] * th1[(3 * 16 + c) * 16 + o]
             + b1i[c] * th1[(6 * 16 + c) * 16 + o];
        c1a += cs2[c] * th1[(4 * 16 + c) * 16 + o]
             + b2i[c] * th1[(8 * 16 + c) * 16 + o];
        k1  += sW1 * th1[(1 * 16 + c) * 16 + o] + sW2 * th1[(5 * 16 + c) * 16 + o]
             + sb1 * th1[(7 * 16 + c) * 16 + o] + sb2 * th1[(9 * 16 + c) * 16 + o];
        o2  += cs1[c] * th2[(0 * 16 + c) * 16 + o]
             + rs2[c] * th2[(2 * 16 + c) * 16 + o]
             + b1i[c] * th2[(4 * 16 + c) * 16 + o];
        k2  += sW1 * th2[(1 * 16 + c) * 16 + o] + sW2 * th2[(3 * 16 + c) * 16 + o]
             + sb1 * th2[(5 * 16 + c) * 16 + o] + sb2 * th2[(6 * 16 + c) * 16 + o];
        o3  += cs2[c] * th3[(1 * 16 + c) * 16 + o]
             + b2i[c] * th3[(4 * 16 + c) * 16 + o];
        k3  += sW1 * th3[(0 * 16 + c) * 16 + o] + sW2 * th3[(2 * 16 + c) * 16 + o]
             + sb1 * th3[(3 * 16 + c) * 16 + o] + sb2 * th3[(5 * 16 + c) * 16 + o];
    }
    R0[gt]   = r0;
    C0[gt]   = c0a + k0 + bias0[o];
    R1[gt]   = r1;
    C1[gt]   = c1a + k1 + bias1[o];
    out2[gt] = o2 + k2 + bias2[o];
    out3[gt] = o3 + k3 + bias3[o];
}

// ---------------------------------------------------------------------------
// k_main (round-14 v6 proven, verbatim): no LDS/barriers, quad-shfl, θ in
// VGPRs, nontemporal output stores.
// ---------------------------------------------------------------------------
__global__ __launch_bounds__(256) void k_main(const float* __restrict__ W1,
                                              const float* __restrict__ W2,
                                              const float* __restrict__ R0,
                                              const float* __restrict__ C0,
                                              const float* __restrict__ R1,
                                              const float* __restrict__ C1,
                                              const float* __restrict__ th0,
                                              const float* __restrict__ th1,
                                              float* __restrict__ out0,
                                              float* __restrict__ out1) {
    int z = blockIdx.z;
    const float* __restrict__ W  = z ? W2 : W1;
    const float* __restrict__ R  = z ? R1 : R0;
    const float* __restrict__ Cc = z ? C1 : C0;
    const float* __restrict__ TH = z ? th1 : th0;
    float* __restrict__ out      = z ? out1 : out0;

    int t   = threadIdx.x;
    int q   = t & 3;
    int jf4 = blockIdx.x * 256 + t;
    int i0  = blockIdx.y * 16;

    float th_reg[4][4][4];
#pragma unroll
    for (int p = 0; p < 4; ++p)
#pragma unroll
        for (int m = 0; m < 4; ++m) {
            float4 v = *(const float4*)(TH + (4 * (q ^ p) + m) * 16 + 4 * q);
            th_reg[p][m][0] = v.x; th_reg[p][m][1] = v.y;
            th_reg[p][m][2] = v.z; th_reg[p][m][3] = v.w;
        }
    float4 cq = ((const float4*)Cc)[jf4];

    const float4* Wf4 = (const float4*)W;
    fvec4*        Onv = (fvec4*)out;

#pragma unroll 2
    for (int ii = 0; ii < 16; ++ii) {
        int i = i0 + ii;
        float4 x  = Wf4[(size_t)i * 4096 + jf4];
        float4 rr = *(const float4*)(R + i * 16 + 4 * q);
        float acc[4] = {cq.x + rr.x, cq.y + rr.y, cq.z + rr.z, cq.w + rr.w};
        float4 xs[4];
        xs[0] = x;
#pragma unroll
        for (int p = 1; p < 4; ++p) {
            xs[p].x = __shfl_xor(x.x, p);
            xs[p].y = __shfl_xor(x.y, p);
            xs[p].z = __shfl_xor(x.z, p);
            xs[p].w = __shfl_xor(x.w, p);
        }
#pragma unroll
        for (int p = 0; p < 4; ++p) {
            float xm0 = xs[p].x, xm1 = xs[p].y, xm2 = xs[p].z, xm3 = xs[p].w;
#pragma unroll
            for (int k = 0; k < 4; ++k)
                acc[k] += xm0 * th_reg[p][0][k] + xm1 * th_reg[p][1][k]
                        + xm2 * th_reg[p][2][k] + xm3 * th_reg[p][3][k];
        }
        fvec4 val = {acc[0], acc[1], acc[2], acc[3]};
        __builtin_nontemporal_store(val, Onv + (size_t)i * 4096 + jf4);
    }
}

extern "C" void kernel_launch(void* const* d_in, const int* in_sizes, int n_in,
                              void* d_out, int out_size, void* d_ws, size_t ws_size,
                              hipStream_t stream) {
    // input order (interleaved theta/bias):
    // 0:W1 1:W2 2:b1 3:b2 4:theta_0 5:bias_0 6:theta_1 7:bias_1
    // 8:theta_2 9:bias_2 10:theta_3 11:bias_3
    const float* W1    = (const float*)d_in[0];
    const float* W2    = (const float*)d_in[1];
    const float* b1    = (const float*)d_in[2];
    const float* b2    = (const float*)d_in[3];
    const float* th0   = (const float*)d_in[4];
    const float* bias0 = (const float*)d_in[5];
    const float* th1   = (const float*)d_in[6];
    const float* bias1 = (const float*)d_in[7];
    const float* th2   = (const float*)d_in[8];
    const float* bias2 = (const float*)d_in[9];
    const float* th3   = (const float*)d_in[10];
    const float* bias3 = (const float*)d_in[11];

    float* out  = (float*)d_out;
    float* out0 = out;
    float* out1 = out + (size_t)NDIM * NDIM * CH;
    float* out2 = out1 + (size_t)NDIM * NDIM * CH;
    float* out3 = out2 + (size_t)NDIM * CH;

    // scratch in the (not-yet-written) out0 region (19.1 MB of 64 MB):
    float* rowpart = out0;                       // [2][16][1024][16]  = 524288
    float* colpart = out0 + 524288;              // [2][128][1024][16] = 4194304
    float* tiletot = out0 + 4718592;             // [2][2048][16]      = 65536

    // workspace layout (proven ≤ 655,616 B budget):
    float* ws      = (float*)d_ws;
    float* rowsumF = ws;                         // [2][1024][16] = 32768
    float* colsumF = ws + 32768;                 // [2][1024][16] = 32768
    float* sums    = ws + 65536;                 // [4][16] = 64
    float* R0      = ws + 65600;                 // 16384 each
    float* C0      = R0 + 16384;
    float* R1      = C0 + 16384;
    float* C1      = R1 + 16384;
    unsigned* ctr  = (unsigned*)(ws + 150000);   // 2 counters, byte 600,000

    hipMemsetAsync(ctr, 0, 2 * sizeof(unsigned), stream);

    k_phase1<<<dim3(FUSED_NB + REDUCE_NB + SMALLS_NB), dim3(256), 0, stream>>>(
        W1, W2, b1, b2, th0, th1, th2, th3, bias0, bias1, bias2, bias3,
        rowpart, colpart, tiletot, rowsumF, colsumF, sums,
        R0, C0, R1, C1, out2, out3, ctr);
    k_main<<<dim3(16, 64, 2), dim3(256), 0, stream>>>(W1, W2, R0, C0, R1, C1,
                                                      th0, th1 + 2 * 256,
                                                      out0, out1);
}

// Round 16
// 89.418 us; speedup vs baseline: 3.3065x; 3.3065x over previous
//
#include <hip/hip_runtime.h>

#define NDIM 1024
#define CH 16
#define ROW_F4 4096   // float4 per W row (1024*16/4)

typedef float fvec4 __attribute__((ext_vector_type(4)));

__device__ inline float4 f4add(float4 a, float4 b) {
    return make_float4(a.x + b.x, a.y + b.y, a.z + b.z, a.w + b.w);
}
__device__ inline float4 f4zero() { return make_float4(0.f, 0.f, 0.f, 0.f); }

// ---------------------------------------------------------------------------
// k_fused (round-8 proven, verbatim): ONE pass over W -> row partials
// (16 j-chunks), col partials (128 i-chunks), per-tile totals.
// Block = 8 rows x 64 cols. LDS 33 KB -> 4 blocks/CU. Partials in out0.
// ---------------------------------------------------------------------------
__global__ __launch_bounds__(256) void k_fused(const float* __restrict__ W1,
                                               const float* __restrict__ W2,
                                               float* __restrict__ rowpart,
                                               float* __restrict__ colpart,
                                               float* __restrict__ tiletot) {
    int t  = threadIdx.x;
    int jt = blockIdx.x, it = blockIdx.y, z = blockIdx.z;
    const float4* base = (const float4*)(z ? W2 : W1)
                       + (size_t)it * 8 * ROW_F4 + jt * 256 + t;
    __shared__ float4 tile[8][258];
    __shared__ float4 rtot[32];
    float4 colacc = f4zero();
#pragma unroll
    for (int r = 0; r < 8; ++r) {
        float4 v = base[(size_t)r * ROW_F4];
        colacc = f4add(colacc, v);
        tile[r][t] = v;
    }
    ((float4*)colpart)[(size_t)(z * 128 + it) * 4096 + jt * 256 + t] = colacc;
    __syncthreads();
    if (t < 32) {   // row partials: r = t>>2, cq = t&3
        int r = t >> 2, cq = t & 3;
        float4 s = f4zero();
#pragma unroll
        for (int jl = 0; jl < 64; ++jl) s = f4add(s, tile[r][jl * 4 + cq]);
        ((float4*)rowpart)[(size_t)(z * 16 + jt) * 4096 + (it * 8 + r) * 4 + cq] = s;
        rtot[t] = s;
    }
    __syncthreads();
    if (t < 4) {    // tile total (16 ch)
        float4 s = f4zero();
#pragma unroll
        for (int r = 0; r < 8; ++r) s = f4add(s, rtot[r * 4 + t]);
        ((float4*)tiletot)[(size_t)(z * 2048 + it * 16 + jt) * 4 + t] = s;
    }
}

// ---------------------------------------------------------------------------
// k_reduce (round-8 proven, verbatim): parallel, coalesced reduction.
// ---------------------------------------------------------------------------
__global__ __launch_bounds__(256) void k_reduce(const float* __restrict__ rowpart,
                                                const float* __restrict__ colpart,
                                                const float* __restrict__ tiletot,
                                                const float* __restrict__ b1,
                                                const float* __restrict__ b2,
                                                float* __restrict__ rowsumF,
                                                float* __restrict__ colsumF,
                                                float* __restrict__ sums) {
    int t = threadIdx.x;
    int b = blockIdx.x;
    if (b < 128) {
        const float4* cp = (const float4*)colpart;
        int o = b * 64 + (t & 63);
        int p = t >> 6;
        int z = o >> 12, rem = o & 4095;
        float4 s = f4zero();
#pragma unroll 8
        for (int k = 0; k < 32; ++k)
            s = f4add(s, cp[(size_t)(z * 128 + p * 32 + k) * 4096 + rem]);
        __shared__ float4 lds[256];
        lds[t] = s;
        __syncthreads();
        if (t < 64) {
            float4 r = f4add(f4add(lds[t], lds[t + 64]),
                             f4add(lds[t + 128], lds[t + 192]));
            ((float4*)colsumF)[o] = r;
        }
    } else if (b < 160) {
        const float4* rp = (const float4*)rowpart;
        int o = (b - 128) * 256 + t;
        int z = o >> 12, rem = o & 4095;
        float4 s = f4zero();
#pragma unroll
        for (int k = 0; k < 16; ++k)
            s = f4add(s, rp[(size_t)(z * 16 + k) * 4096 + rem]);
        ((float4*)rowsumF)[o] = s;
    } else if (b == 160) {
        int c = t & 15, p = (t >> 4) & 7, z = t >> 7;
        float s = 0.f;
#pragma unroll 8
        for (int m = 0; m < 256; ++m)
            s += tiletot[(size_t)(z * 2048 + p * 256 + m) * 16 + c];
        __shared__ float ldsA[2][8][16];
        ldsA[z][p][c] = s;
        __syncthreads();
        if (t < 32) {
            int zz = t >> 4, cc = t & 15;
            float r = 0.f;
#pragma unroll
            for (int q = 0; q < 8; ++q) r += ldsA[zz][q][cc];
            sums[zz * 16 + cc] = r;
        }
    } else {
        int w = b - 161;
        const float* src = w ? b2 : b1;
        int c = t & 15, p = t >> 4;
        float s = 0.f;
#pragma unroll 8
        for (int m = 0; m < 64; ++m)
            s += src[(size_t)(p * 64 + m) * 16 + c];
        __shared__ float ldsB[16][16];
        ldsB[p][c] = s;
        __syncthreads();
        if (t < 16) {
            float r = 0.f;
#pragma unroll
            for (int q = 0; q < 16; ++q) r += ldsB[q][t];
            sums[32 + w * 16 + t] = r;
        }
    }
}

// ---------------------------------------------------------------------------
// k_smalls (round-8 proven, verbatim): all O(N) outputs from finalized sums.
// ---------------------------------------------------------------------------
__global__ __launch_bounds__(256) void k_smalls(const float* __restrict__ rowsum,
                                                const float* __restrict__ colsum,
                                                const float* __restrict__ sums,
                                                const float* __restrict__ b1,
                                                const float* __restrict__ b2,
                                                const float* __restrict__ th0,
                                                const float* __restrict__ th1,
                                                const float* __restrict__ th2,
                                                const float* __restrict__ th3,
                                                const float* __restrict__ bias0,
                                                const float* __restrict__ bias1,
                                                const float* __restrict__ bias2,
                                                const float* __restrict__ bias3,
                                                float* __restrict__ R0, float* __restrict__ C0,
                                                float* __restrict__ R1, float* __restrict__ C1,
                                                float* __restrict__ out2, float* __restrict__ out3) {
    int gt = blockIdx.x * 256 + threadIdx.x;
    int i = gt >> 4, o = gt & 15;
    const float* rs1 = rowsum + i * 16;
    const float* rs2 = rowsum + 16384 + i * 16;
    const float* cs1 = colsum + i * 16;
    const float* cs2 = colsum + 16384 + i * 16;
    const float* b1i = b1 + i * 16;
    const float* b2i = b2 + i * 16;
    float r0 = 0.f, c0a = 0.f, r1 = 0.f, c1a = 0.f, o2 = 0.f, o3 = 0.f;
    float k0 = 0.f, k1 = 0.f, k2 = 0.f, k3 = 0.f;
#pragma unroll
    for (int c = 0; c < 16; ++c) {
        float sW1 = sums[c], sW2 = sums[16 + c], sb1 = sums[32 + c], sb2 = sums[48 + c];
        r0  += rs1[c] * th0[(1 * 16 + c) * 16 + o];
        c0a += cs1[c] * th0[(2 * 16 + c) * 16 + o]
             + rs2[c] * th0[(4 * 16 + c) * 16 + o]
             + b1i[c] * th0[(6 * 16 + c) * 16 + o];
        k0  += sW1 * th0[(3 * 16 + c) * 16 + o] + sW2 * th0[(5 * 16 + c) * 16 + o]
             + sb1 * th0[(7 * 16 + c) * 16 + o] + sb2 * th0[(8 * 16 + c) * 16 + o];
        r1  += cs1[c] * th1[(0 * 16 + c) * 16 + o]
             + rs2[c] * th1[(3 * 16 + c) * 16 + o]
             + b1i[c] * th1[(6 * 16 + c) * 16 + o];
        c1a += cs2[c] * th1[(4 * 16 + c) * 16 + o]
             + b2i[c] * th1[(8 * 16 + c) * 16 + o];
        k1  += sW1 * th1[(1 * 16 + c) * 16 + o] + sW2 * th1[(5 * 16 + c) * 16 + o]
             + sb1 * th1[(7 * 16 + c) * 16 + o] + sb2 * th1[(9 * 16 + c) * 16 + o];
        o2  += cs1[c] * th2[(0 * 16 + c) * 16 + o]
             + rs2[c] * th2[(2 * 16 + c) * 16 + o]
             + b1i[c] * th2[(4 * 16 + c) * 16 + o];
        k2  += sW1 * th2[(1 * 16 + c) * 16 + o] + sW2 * th2[(3 * 16 + c) * 16 + o]
             + sb1 * th2[(5 * 16 + c) * 16 + o] + sb2 * th2[(6 * 16 + c) * 16 + o];
        o3  += cs2[c] * th3[(1 * 16 + c) * 16 + o]
             + b2i[c] * th3[(4 * 16 + c) * 16 + o];
        k3  += sW1 * th3[(0 * 16 + c) * 16 + o] + sW2 * th3[(2 * 16 + c) * 16 + o]
             + sb1 * th3[(3 * 16 + c) * 16 + o] + sb2 * th3[(5 * 16 + c) * 16 + o];
    }
    R0[gt]   = r0;
    C0[gt]   = c0a + k0 + bias0[o];
    R1[gt]   = r1;
    C1[gt]   = c1a + k1 + bias1[o];
    out2[gt] = o2 + k2 + bias2[o];
    out3[gt] = o3 + k3 + bias3[o];
}

// ---------------------------------------------------------------------------
// k_main (round-14 v6 proven, verbatim): no LDS/barriers, quad-shfl, θ in
// VGPRs, nontemporal output stores.
// ---------------------------------------------------------------------------
__global__ __launch_bounds__(256) void k_main(const float* __restrict__ W1,
                                              const float* __restrict__ W2,
                                              const float* __restrict__ R0,
                                              const float* __restrict__ C0,
                                              const float* __restrict__ R1,
                                              const float* __restrict__ C1,
                                              const float* __restrict__ th0,
                                              const float* __restrict__ th1,
                                              float* __restrict__ out0,
                                              float* __restrict__ out1) {
    int z = blockIdx.z;
    const float* __restrict__ W  = z ? W2 : W1;
    const float* __restrict__ R  = z ? R1 : R0;
    const float* __restrict__ Cc = z ? C1 : C0;
    const float* __restrict__ TH = z ? th1 : th0;
    float* __restrict__ out      = z ? out1 : out0;

    int t   = threadIdx.x;
    int q   = t & 3;
    int jf4 = blockIdx.x * 256 + t;
    int i0  = blockIdx.y * 16;

    float th_reg[4][4][4];
#pragma unroll
    for (int p = 0; p < 4; ++p)
#pragma unroll
        for (int m = 0; m < 4; ++m) {
            float4 v = *(const float4*)(TH + (4 * (q ^ p) + m) * 16 + 4 * q);
            th_reg[p][m][0] = v.x; th_reg[p][m][1] = v.y;
            th_reg[p][m][2] = v.z; th_reg[p][m][3] = v.w;
        }
    float4 cq = ((const float4*)Cc)[jf4];

    const float4* Wf4 = (const float4*)W;
    fvec4*        Onv = (fvec4*)out;

#pragma unroll 2
    for (int ii = 0; ii < 16; ++ii) {
        int i = i0 + ii;
        float4 x  = Wf4[(size_t)i * 4096 + jf4];
        float4 rr = *(const float4*)(R + i * 16 + 4 * q);
        float acc[4] = {cq.x + rr.x, cq.y + rr.y, cq.z + rr.z, cq.w + rr.w};
        float4 xs[4];
        xs[0] = x;
#pragma unroll
        for (int p = 1; p < 4; ++p) {
            xs[p].x = __shfl_xor(x.x, p);
            xs[p].y = __shfl_xor(x.y, p);
            xs[p].z = __shfl_xor(x.z, p);
            xs[p].w = __shfl_xor(x.w, p);
        }
#pragma unroll
        for (int p = 0; p < 4; ++p) {
            float xm0 = xs[p].x, xm1 = xs[p].y, xm2 = xs[p].z, xm3 = xs[p].w;
#pragma unroll
            for (int k = 0; k < 4; ++k)
                acc[k] += xm0 * th_reg[p][0][k] + xm1 * th_reg[p][1][k]
                        + xm2 * th_reg[p][2][k] + xm3 * th_reg[p][3][k];
        }
        fvec4 val = {acc[0], acc[1], acc[2], acc[3]};
        __builtin_nontemporal_store(val, Onv + (size_t)i * 4096 + jf4);
    }
}

extern "C" void kernel_launch(void* const* d_in, const int* in_sizes, int n_in,
                              void* d_out, int out_size, void* d_ws, size_t ws_size,
                              hipStream_t stream) {
    // input order (interleaved theta/bias):
    // 0:W1 1:W2 2:b1 3:b2 4:theta_0 5:bias_0 6:theta_1 7:bias_1
    // 8:theta_2 9:bias_2 10:theta_3 11:bias_3
    const float* W1    = (const float*)d_in[0];
    const float* W2    = (const float*)d_in[1];
    const float* b1    = (const float*)d_in[2];
    const float* b2    = (const float*)d_in[3];
    const float* th0   = (const float*)d_in[4];
    const float* bias0 = (const float*)d_in[5];
    const float* th1   = (const float*)d_in[6];
    const float* bias1 = (const float*)d_in[7];
    const float* th2   = (const float*)d_in[8];
    const float* bias2 = (const float*)d_in[9];
    const float* th3   = (const float*)d_in[10];
    const float* bias3 = (const float*)d_in[11];

    float* out  = (float*)d_out;
    float* out0 = out;
    float* out1 = out + (size_t)NDIM * NDIM * CH;
    float* out2 = out1 + (size_t)NDIM * NDIM * CH;
    float* out3 = out2 + (size_t)NDIM * CH;

    // scratch in the (not-yet-written) out0 region (19.1 MB of 64 MB):
    float* rowpart = out0;                       // [2][16][1024][16]  = 524288
    float* colpart = out0 + 524288;              // [2][128][1024][16] = 4194304
    float* tiletot = out0 + 4718592;             // [2][2048][16]      = 65536

    // workspace: 131,136 floats = 524,544 B (proven budget)
    float* ws      = (float*)d_ws;
    float* rowsumF = ws;                         // [2][1024][16] = 32768
    float* colsumF = ws + 32768;                 // [2][1024][16] = 32768
    float* sums    = ws + 65536;                 // [4][16] = 64
    float* R0      = ws + 65600;                 // 16384 each
    float* C0      = R0 + 16384;
    float* R1      = C0 + 16384;
    float* C1      = R1 + 16384;

    k_fused<<<dim3(16, 128, 2), dim3(256), 0, stream>>>(W1, W2, rowpart, colpart, tiletot);
    k_reduce<<<dim3(163), dim3(256), 0, stream>>>(rowpart, colpart, tiletot, b1, b2,
                                                  rowsumF, colsumF, sums);
    k_smalls<<<dim3(64), dim3(256), 0, stream>>>(rowsumF, colsumF, sums, b1, b2,
                                                 th0, th1, th2, th3,
                                                 bias0, bias1, bias2, bias3,
                                                 R0, C0, R1, C1, out2, out3);
    k_main<<<dim3(16, 64, 2), dim3(256), 0, stream>>>(W1, W2, R0, C0, R1, C1,
                                                      th0, th1 + 2 * 256,
                                                      out0, out1);
}